// Round 15
// baseline (234.802 us; speedup 1.0000x reference)
//
#include <hip/hip_runtime.h>

// Sparse deconv (27-tap, 64->96ch) + BN + ReLU on MI355X.
// R13 base (4-buffer LDS-B rotation staged by global_load_lds, barrier per
// 2 taps, M=48 rows/wave, 1-deep gather prefetch, 2-deep srcmap prefetch,
// merged prep, bf16 staging) plus:
//  - per-rt-tile MFMA skip, rt-outer form (B preloaded, 3 uniform branches)
//  - direct per-rt srcmap loads (no ds_bpermute on the LDS pipe)

#define N_VOX   200000
#define INC     64
#define OUTC    96
#define NOFF    26
#define MROWS   192           // rows per block (4 waves x 48)
#define NBLK    1042          // ceil(200000 / 192)
#define NPAD    200192        // >= NBLK*MROWS, padded srcmap stride
#define EPSV    1e-5f

using bf16x8 = __attribute__((ext_vector_type(8))) short;
using f32x4  = __attribute__((ext_vector_type(4))) float;

__device__ inline unsigned short f2bf(float x) {
    union { float f; unsigned u; } v; v.f = x;
    unsigned r = (v.u + 0x7FFFu + ((v.u >> 16) & 1u)) >> 16;
    return (unsigned short)r;
}

__device__ __forceinline__ void gload_lds16(const void* g, void* l) {
    __builtin_amdgcn_global_load_lds(
        (const __attribute__((address_space(1))) void*)g,
        (__attribute__((address_space(3))) void*)l, 16, 0, 0);
}

// Merged prep: fcvt (feats->bf16) | fill_src (scatter inversion) | wprep
// (weights->bf16 fragment order). All independent; branch on blockIdx.
__global__ void prep_kernel(const float* __restrict__ feats,
                            const float* __restrict__ Wc,
                            const float* __restrict__ Woff,
                            const int* __restrict__ in_idx,
                            const int* __restrict__ out_idx,
                            int P, int fill_blocks,
                            unsigned short* __restrict__ featsb,
                            unsigned short* __restrict__ Wb,
                            int* __restrict__ srcmap) {
    const int FCVT_BLOCKS = (N_VOX * INC / 8 + 255) / 256;   // 6250
    int b = blockIdx.x;
    int t = threadIdx.x;
    if (b < FCVT_BLOCKS) {
        int i = b * 256 + t;
        if (i < N_VOX * INC / 8) {
            const float4* src = (const float4*)feats + (size_t)i * 2;
            float4 f0 = src[0], f1 = src[1];
            bf16x8 v;
            v[0] = (short)f2bf(f0.x); v[1] = (short)f2bf(f0.y);
            v[2] = (short)f2bf(f0.z); v[3] = (short)f2bf(f0.w);
            v[4] = (short)f2bf(f1.x); v[5] = (short)f2bf(f1.y);
            v[6] = (short)f2bf(f1.z); v[7] = (short)f2bf(f1.w);
            *(bf16x8*)(featsb + (size_t)i * 8) = v;
        }
        return;
    }
    b -= FCVT_BLOCKS;
    if (b < fill_blocks) {
        int idx = b * 256 + t;
        if (idx < NOFF * P) {
            int dst = out_idx[idx];
            if (dst < N_VOX) {
                int k = idx / P;
                srcmap[(size_t)k * NPAD + dst] = in_idx[idx];
            }
        }
        return;
    }
    b -= fill_blocks;
    {
        int g = b * 256 + t;                  // 27*2*6*64 = 20736 entries
        if (g >= 27 * 2 * 6 * 64) return;
        int lane = g & 63;
        int gg   = g >> 6;                    // m*12 + s*6 + ct
        int ct   = gg % 6;
        int s    = (gg / 6) % 2;
        int m    = gg / 12;
        const float* W = (m == 26) ? Wc : (Woff + (size_t)m * INC * OUTC);
        int k0 = s * 32 + (lane >> 4) * 8;
        int c  = ct * 16 + (lane & 15);
        bf16x8 v;
        #pragma unroll
        for (int e = 0; e < 8; ++e)
            v[e] = (short)f2bf(W[(size_t)(k0 + e) * OUTC + c]);
        *(bf16x8*)(Wb + (size_t)g * 8) = v;
    }
}

// tap order: idx 0 -> center (Wb[26], identity src), idx i>=1 -> offset i-1.
// 4-buffer B rotation: tap idx reads buf idx&3; iter idx stages tap idx+2
// (weights Wb[idx+1]) into buf (idx+2)&3; barrier after odd iters only.
// srcmap: smv[rt] = offset idx rows (consumed by iter idx's prefetch gather
// for tap idx+1); smn loaded for offset idx+1 during iter idx.
template<int STAGE_BF16>
__global__ __launch_bounds__(256, 3)
void conv_mfma_kernel(const unsigned short* __restrict__ featsb,
                      const unsigned short* __restrict__ Wb,
                      const int* __restrict__ srcmap,
                      float* __restrict__ outf,
                      unsigned short* __restrict__ stg,
                      float* __restrict__ pstats) {
    __shared__ __align__(16) unsigned short Wlds[4][6144];   // 4 x 12 KB

    const int t     = threadIdx.x;
    const int wid   = t >> 6;
    const int lane  = t & 63;
    const int blk   = blockIdx.x;
    const int rbase = blk * MROWS + wid * 48;   // this wave's 48 output rows
    const int row16 = lane & 15;
    const int kgrp  = lane >> 4;                // 0..3

    f32x4  acc[3][6] = {};
    bf16x8 aC[3][2], aN[3][2];
    int smv[3];
    int hasC, hasN;

    // ---- prologue: stage taps 0 (Wb[26]) and 1 (Wb[0]) into bufs 0,1 ----
    #pragma unroll
    for (int i = 0; i < 3; ++i)
        gload_lds16(Wb + (size_t)26 * 6144 + (size_t)(t + 256 * i) * 8,
                    &Wlds[0][(t + 256 * i) * 8]);
    #pragma unroll
    for (int i = 0; i < 3; ++i)
        gload_lds16(Wb + (size_t)(t + 256 * i) * 8,
                    &Wlds[1][(t + 256 * i) * 8]);

    // srcmap for offset 0 (consumed by iter 0's gather for tap 1)
    #pragma unroll
    for (int rt = 0; rt < 3; ++rt)
        smv[rt] = srcmap[(unsigned)(rbase + rt * 16 + row16)];

    // gather center rows -> aC (identity src; OOB rows read zeroed pad row)
    #pragma unroll
    for (int rt = 0; rt < 3; ++rt) {
        int row = rbase + rt * 16 + row16;
        unsigned src = (row < N_VOX ? row : N_VOX);
        const unsigned short* fr = featsb + (size_t)src * INC + kgrp * 8;
        aC[rt][0] = *(const bf16x8*)fr;
        aC[rt][1] = *(const bf16x8*)(fr + 32);
    }
    hasC = 0x7;
    __syncthreads();

    for (int idx = 0; idx < 27; ++idx) {
        // 1. srcmap for offset idx+1 (consumed next iter)
        int smn[3];
        if (idx <= 24) {
            #pragma unroll
            for (int rt = 0; rt < 3; ++rt)
                smn[rt] = srcmap[(size_t)(idx + 1) * NPAD + rbase + rt * 16 + row16];
        }

        // 2. gather A for next tap (offset idx, exec-masked, per-rt ballot)
        //    + stage B for tap idx+2 (Wb[idx+1]) into buf (idx+2)&3
        int hn = 0;
        if (idx <= 25) {
            #pragma unroll
            for (int rt = 0; rt < 3; ++rt) {
                int s = smv[rt];
                if (__ballot(s >= 0)) hn |= (1 << rt);
                bf16x8 g0 = {}, g1 = {};
                if (s >= 0) {
                    const unsigned short* fr = featsb + (unsigned)s * INC + kgrp * 8;
                    g0 = *(const bf16x8*)fr;
                    g1 = *(const bf16x8*)(fr + 32);
                }
                aN[rt][0] = g0; aN[rt][1] = g1;
            }
        }
        hasN = __builtin_amdgcn_readfirstlane(hn);
        if (idx <= 24) {
            #pragma unroll
            for (int i = 0; i < 3; ++i)
                gload_lds16(Wb + (size_t)(idx + 1) * 6144 + (size_t)(t + 256 * i) * 8,
                            &Wlds[(idx + 2) & 3][(t + 256 * i) * 8]);
        }

        // 3. MFMA current tap: preload 12 B fragments (pipelined ds_reads),
        //    then rt-outer with 3 wave-uniform skip branches
        {
            const unsigned short* WL = Wlds[idx & 3];
            bf16x8 B0[6], B1[6];
            #pragma unroll
            for (int ct = 0; ct < 6; ++ct) {
                B0[ct] = *(const bf16x8*)&WL[(size_t)ct * 512 + lane * 8];
                B1[ct] = *(const bf16x8*)&WL[(size_t)(6 + ct) * 512 + lane * 8];
            }
            #pragma unroll
            for (int rt = 0; rt < 3; ++rt) {
                if (hasC & (1 << rt)) {
                    #pragma unroll
                    for (int ct = 0; ct < 6; ++ct) {
                        acc[rt][ct] = __builtin_amdgcn_mfma_f32_16x16x32_bf16(aC[rt][0], B0[ct], acc[rt][ct], 0, 0, 0);
                        acc[rt][ct] = __builtin_amdgcn_mfma_f32_16x16x32_bf16(aC[rt][1], B1[ct], acc[rt][ct], 0, 0, 0);
                    }
                }
            }
        }

        // 4. barrier once per 2-tap superstep
        if (idx & 1) __syncthreads();

        #pragma unroll
        for (int rt = 0; rt < 3; ++rt) {
            aC[rt][0] = aN[rt][0]; aC[rt][1] = aN[rt][1];
            smv[rt] = (idx <= 24) ? smn[rt] : -1;
        }
        hasC = hasN;
    }

    // ---- BN partial stats: lane -> wave shfl -> LDS cross-wave ----
    float s6[6], q6[6];
    #pragma unroll
    for (int ct = 0; ct < 6; ++ct) {
        float s = 0.f, q = 0.f;
        #pragma unroll
        for (int rt = 0; rt < 3; ++rt) {
            f32x4 a = acc[rt][ct];
            s += a[0] + a[1] + a[2] + a[3];
            q += a[0]*a[0] + a[1]*a[1] + a[2]*a[2] + a[3]*a[3];
        }
        s += __shfl_xor(s, 16); q += __shfl_xor(q, 16);
        s += __shfl_xor(s, 32); q += __shfl_xor(q, 32);
        s6[ct] = s; q6[ct] = q;
    }
    float* sred = (float*)Wlds;      // buf 0 region; last MFMA read buf 2
    if (lane < 16) {
        #pragma unroll
        for (int ct = 0; ct < 6; ++ct) {
            sred[wid * 96 + ct * 16 + lane]       = s6[ct];
            sred[384 + wid * 96 + ct * 16 + lane] = q6[ct];
        }
    }
    __syncthreads();
    if (t < 96) {
        float s = sred[t] + sred[96 + t] + sred[192 + t] + sred[288 + t];
        pstats[(size_t)t * NBLK + blk] = s;
    } else if (t < 192) {
        int c = t - 96;
        float q = sred[384 + c] + sred[480 + c] + sred[576 + c] + sred[672 + c];
        pstats[(size_t)(96 + c) * NBLK + blk] = q;
    }

    // ---- store conv output ----
    #pragma unroll
    for (int rt = 0; rt < 3; ++rt) {
        #pragma unroll
        for (int ct = 0; ct < 6; ++ct) {
            #pragma unroll
            for (int j = 0; j < 4; ++j) {
                int row = rbase + rt * 16 + kgrp * 4 + j;
                if (row < N_VOX) {
                    if (STAGE_BF16)
                        stg[(size_t)row * OUTC + ct * 16 + row16] = f2bf(acc[rt][ct][j]);
                    else
                        outf[(size_t)row * OUTC + ct * 16 + row16] = acc[rt][ct][j];
                }
            }
        }
    }
}

__global__ void stats_reduce_kernel(const float* __restrict__ pstats,
                                    const float* __restrict__ gamma,
                                    const float* __restrict__ beta,
                                    float* __restrict__ scsh) {
    int c = blockIdx.x;               // 0..95
    int t = threadIdx.x;
    float s = 0.f, q = 0.f;
    for (int i = t; i < NBLK; i += 256) {
        s += pstats[(size_t)c * NBLK + i];
        q += pstats[(size_t)(96 + c) * NBLK + i];
    }
    #pragma unroll
    for (int d = 1; d < 64; d <<= 1) {
        s += __shfl_xor(s, d);
        q += __shfl_xor(q, d);
    }
    __shared__ float rs[4], rq[4];
    if ((t & 63) == 0) { rs[t >> 6] = s; rq[t >> 6] = q; }
    __syncthreads();
    if (t == 0) {
        s = rs[0] + rs[1] + rs[2] + rs[3];
        q = rq[0] + rq[1] + rq[2] + rq[3];
        float inv_n = 1.0f / (float)N_VOX;
        float mean = s * inv_n;
        float var  = q * inv_n - mean * mean;
        float sc   = gamma[c] * rsqrtf(var + EPSV);
        scsh[c]      = sc;
        scsh[96 + c] = beta[c] - mean * sc;
    }
}

__global__ void apply_bn_bf16_kernel(const unsigned short* __restrict__ stg,
                                     float* __restrict__ out,
                                     const float* __restrict__ scsh) {
    __shared__ float sc[OUTC], sh[OUTC];
    int t = threadIdx.x;
    if (t < OUTC) { sc[t] = scsh[t]; sh[t] = scsh[96 + t]; }
    __syncthreads();
    const int total8 = N_VOX * OUTC / 8;
    for (int i = blockIdx.x * blockDim.x + t; i < total8; i += gridDim.x * blockDim.x) {
        bf16x8 v = *(const bf16x8*)(stg + (size_t)i * 8);
        int c = (i % 12) * 8;
        float o[8];
        #pragma unroll
        for (int j = 0; j < 8; ++j) {
            union { unsigned u; float f; } w; w.u = (unsigned)(unsigned short)v[j] << 16;
            o[j] = fmaxf(fmaf(w.f, sc[c + j], sh[c + j]), 0.f);
        }
        float4* dst = (float4*)(out + (size_t)i * 8);
        dst[0] = make_float4(o[0], o[1], o[2], o[3]);
        dst[1] = make_float4(o[4], o[5], o[6], o[7]);
    }
}

__global__ void apply_bn_fp32_kernel(float* __restrict__ out,
                                     const float* __restrict__ scsh) {
    __shared__ float sc[OUTC], sh[OUTC];
    int t = threadIdx.x;
    if (t < OUTC) { sc[t] = scsh[t]; sh[t] = scsh[96 + t]; }
    __syncthreads();
    const int total4 = N_VOX * OUTC / 4;
    for (int i = blockIdx.x * blockDim.x + t; i < total4; i += gridDim.x * blockDim.x) {
        float4 v = ((float4*)out)[i];
        int c = (i * 4) % OUTC;
        v.x = fmaxf(fmaf(v.x, sc[c    ], sh[c    ]), 0.f);
        v.y = fmaxf(fmaf(v.y, sc[c + 1], sh[c + 1]), 0.f);
        v.z = fmaxf(fmaf(v.z, sc[c + 2], sh[c + 2]), 0.f);
        v.w = fmaxf(fmaf(v.w, sc[c + 3], sh[c + 3]), 0.f);
        ((float4*)out)[i] = v;
    }
}

extern "C" void kernel_launch(void* const* d_in, const int* in_sizes, int n_in,
                              void* d_out, int out_size, void* d_ws, size_t ws_size,
                              hipStream_t stream) {
    const float* feats   = (const float*)d_in[0];
    const float* Wc      = (const float*)d_in[1];
    const float* Woff    = (const float*)d_in[2];
    const float* gamma   = (const float*)d_in[3];
    const float* beta    = (const float*)d_in[4];
    const int*   in_idx  = (const int*)d_in[5];
    const int*   out_idx = (const int*)d_in[6];
    const int P = in_sizes[5] / NOFF;

    char* w = (char*)d_ws;
    int* srcmap = (int*)w;                   w += (size_t)NOFF * NPAD * 4;    // 20.82 MB
    unsigned short* Wb = (unsigned short*)w; w += (size_t)27 * 6144 * 2;      // 332 KB
    float* pstats = (float*)w;               w += (size_t)192 * NBLK * 4;     // 0.8 MB
    float* scsh = (float*)w;                 w += 256 * 4;
    unsigned short* featsb = (unsigned short*)w;
    w += (size_t)(N_VOX + 1) * INC * 2;                                        // 25.6 MB (+pad row)
    unsigned short* stg = (unsigned short*)w;
    size_t need_stg = (size_t)(w - (char*)d_ws) + (size_t)N_VOX * OUTC * 2;   // +38.4 MB
    bool use_stg = (ws_size >= need_stg);

    hipMemsetAsync(srcmap, 0xFF, (size_t)NOFF * NPAD * 4, stream);
    hipMemsetAsync(featsb + (size_t)N_VOX * INC, 0, INC * 2, stream);         // zero pad row

    const int FCVT_BLOCKS = (N_VOX * INC / 8 + 255) / 256;
    const int fill_blocks = (NOFF * P + 255) / 256;
    const int WPREP_BLOCKS = (27 * 2 * 6 * 64 + 255) / 256;
    prep_kernel<<<FCVT_BLOCKS + fill_blocks + WPREP_BLOCKS, 256, 0, stream>>>(
        feats, Wc, Woff, in_idx, out_idx, P, fill_blocks, featsb, Wb, srcmap);

    float* out = (float*)d_out;
    if (use_stg) {
        conv_mfma_kernel<1><<<NBLK, 256, 0, stream>>>(featsb, Wb, srcmap, out, stg, pstats);
        stats_reduce_kernel<<<96, 256, 0, stream>>>(pstats, gamma, beta, scsh);
        apply_bn_bf16_kernel<<<2048, 256, 0, stream>>>(stg, out, scsh);
    } else {
        conv_mfma_kernel<0><<<NBLK, 256, 0, stream>>>(featsb, Wb, srcmap, out, stg, pstats);
        stats_reduce_kernel<<<96, 256, 0, stream>>>(pstats, gamma, beta, scsh);
        apply_bn_fp32_kernel<<<2048, 256, 0, stream>>>(out, scsh);
    }
}

// Round 16
// 114.490 us; speedup vs baseline: 2.0508x; 2.0508x over previous
//
#include <hip/hip_runtime.h>

// Sparse deconv (27-tap, 64->96ch) + BN + ReLU on MI355X.
// R13 (verified best, 114.5 us): 4-buffer LDS-B rotation staged by
// global_load_lds, barrier once per 2 taps, M=48 rows/wave, 1-deep gather
// prefetch, 2-deep srcmap prefetch, merged prep kernel, bf16 staging.

#define N_VOX   200000
#define INC     64
#define OUTC    96
#define NOFF    26
#define MROWS   192           // rows per block (4 waves x 48)
#define NBLK    1042          // ceil(200000 / 192)
#define NPAD    200192        // >= NBLK*MROWS, padded srcmap stride
#define EPSV    1e-5f

using bf16x8 = __attribute__((ext_vector_type(8))) short;
using f32x4  = __attribute__((ext_vector_type(4))) float;

__device__ inline unsigned short f2bf(float x) {
    union { float f; unsigned u; } v; v.f = x;
    unsigned r = (v.u + 0x7FFFu + ((v.u >> 16) & 1u)) >> 16;
    return (unsigned short)r;
}

__device__ __forceinline__ void gload_lds16(const void* g, void* l) {
    __builtin_amdgcn_global_load_lds(
        (const __attribute__((address_space(1))) void*)g,
        (__attribute__((address_space(3))) void*)l, 16, 0, 0);
}

// Merged prep: fcvt (feats->bf16) | fill_src (scatter inversion) | wprep
// (weights->bf16 fragment order). All independent; branch on blockIdx.
__global__ void prep_kernel(const float* __restrict__ feats,
                            const float* __restrict__ Wc,
                            const float* __restrict__ Woff,
                            const int* __restrict__ in_idx,
                            const int* __restrict__ out_idx,
                            int P, int fill_blocks,
                            unsigned short* __restrict__ featsb,
                            unsigned short* __restrict__ Wb,
                            int* __restrict__ srcmap) {
    const int FCVT_BLOCKS = (N_VOX * INC / 8 + 255) / 256;   // 6250
    int b = blockIdx.x;
    int t = threadIdx.x;
    if (b < FCVT_BLOCKS) {
        int i = b * 256 + t;
        if (i < N_VOX * INC / 8) {
            const float4* src = (const float4*)feats + (size_t)i * 2;
            float4 f0 = src[0], f1 = src[1];
            bf16x8 v;
            v[0] = (short)f2bf(f0.x); v[1] = (short)f2bf(f0.y);
            v[2] = (short)f2bf(f0.z); v[3] = (short)f2bf(f0.w);
            v[4] = (short)f2bf(f1.x); v[5] = (short)f2bf(f1.y);
            v[6] = (short)f2bf(f1.z); v[7] = (short)f2bf(f1.w);
            *(bf16x8*)(featsb + (size_t)i * 8) = v;
        }
        return;
    }
    b -= FCVT_BLOCKS;
    if (b < fill_blocks) {
        int idx = b * 256 + t;
        if (idx < NOFF * P) {
            int dst = out_idx[idx];
            if (dst < N_VOX) {
                int k = idx / P;
                srcmap[(size_t)k * NPAD + dst] = in_idx[idx];
            }
        }
        return;
    }
    b -= fill_blocks;
    {
        int g = b * 256 + t;                  // 27*2*6*64 = 20736 entries
        if (g >= 27 * 2 * 6 * 64) return;
        int lane = g & 63;
        int gg   = g >> 6;                    // m*12 + s*6 + ct
        int ct   = gg % 6;
        int s    = (gg / 6) % 2;
        int m    = gg / 12;
        const float* W = (m == 26) ? Wc : (Woff + (size_t)m * INC * OUTC);
        int k0 = s * 32 + (lane >> 4) * 8;
        int c  = ct * 16 + (lane & 15);
        bf16x8 v;
        #pragma unroll
        for (int e = 0; e < 8; ++e)
            v[e] = (short)f2bf(W[(size_t)(k0 + e) * OUTC + c]);
        *(bf16x8*)(Wb + (size_t)g * 8) = v;
    }
}

// tap order: idx 0 -> center (Wb[26], identity src), idx i>=1 -> offset i-1.
// 4-buffer B rotation: tap idx reads buf idx&3; iter idx stages tap idx+2
// (weights Wb[idx+1]) into buf (idx+2)&3; barrier after odd iters only.
template<int STAGE_BF16>
__global__ __launch_bounds__(256, 3)
void conv_mfma_kernel(const unsigned short* __restrict__ featsb,
                      const unsigned short* __restrict__ Wb,
                      const int* __restrict__ srcmap,
                      float* __restrict__ outf,
                      unsigned short* __restrict__ stg,
                      float* __restrict__ pstats) {
    __shared__ __align__(16) unsigned short Wlds[4][6144];   // 4 x 12 KB

    const int t     = threadIdx.x;
    const int wid   = t >> 6;
    const int lane  = t & 63;
    const int blk   = blockIdx.x;
    const int rbase = blk * MROWS + wid * 48;   // this wave's 48 output rows
    const int row16 = lane & 15;
    const int kgrp  = lane >> 4;                // 0..3

    f32x4  acc[3][6] = {};
    bf16x8 aC[3][2], aN[3][2];

    // ---- prologue: stage taps 0 (Wb[26]) and 1 (Wb[0]) into bufs 0,1 ----
    #pragma unroll
    for (int i = 0; i < 3; ++i)
        gload_lds16(Wb + (size_t)26 * 6144 + (size_t)(t + 256 * i) * 8,
                    &Wlds[0][(t + 256 * i) * 8]);
    #pragma unroll
    for (int i = 0; i < 3; ++i)
        gload_lds16(Wb + (size_t)(t + 256 * i) * 8,
                    &Wlds[1][(t + 256 * i) * 8]);

    // srcmap prefetch for tap 1 (offset 0): 1 coalesced load, lanes 0..47
    int sm_next = (lane < 48) ? srcmap[rbase + lane] : -1;

    // gather center rows -> aC (identity src; OOB rows read zeroed pad row)
    bool has_cur = true;
    #pragma unroll
    for (int rt = 0; rt < 3; ++rt) {
        int row = rbase + rt * 16 + row16;
        int src = row < N_VOX ? row : N_VOX;
        const unsigned short* fr = featsb + (size_t)src * INC + kgrp * 8;
        aC[rt][0] = *(const bf16x8*)fr;
        aC[rt][1] = *(const bf16x8*)(fr + 32);
    }
    __syncthreads();

    for (int idx = 0; idx < 27; ++idx) {
        // 1. srcmap prefetch, 2 taps ahead (offset idx+1)
        int sm_next2 = -1;
        if (idx <= 24 && lane < 48)
            sm_next2 = srcmap[(size_t)(idx + 1) * NPAD + rbase + lane];

        // 2. gather A for next tap (offset idx, exec-masked)
        //    + stage B for tap idx+2 (Wb[idx+1]) into buf (idx+2)&3
        bool has_next = false;
        if (idx <= 25) {
            bool any = false;
            #pragma unroll
            for (int rt = 0; rt < 3; ++rt) {
                int src = __shfl(sm_next, rt * 16 + row16);
                bf16x8 g0 = {}, g1 = {};
                if (src >= 0) {
                    const unsigned short* fr = featsb + (size_t)src * INC + kgrp * 8;
                    g0 = *(const bf16x8*)fr;
                    g1 = *(const bf16x8*)(fr + 32);
                    any = true;
                }
                aN[rt][0] = g0; aN[rt][1] = g1;
            }
            has_next = __ballot(any) != 0ull;
        }
        if (idx <= 24) {
            #pragma unroll
            for (int i = 0; i < 3; ++i)
                gload_lds16(Wb + (size_t)(idx + 1) * 6144 + (size_t)(t + 256 * i) * 8,
                            &Wlds[(idx + 2) & 3][(t + 256 * i) * 8]);
        }

        // 3. MFMA current tap (B via ds_read from buf idx&3)
        if (has_cur) {
            const unsigned short* WL = Wlds[idx & 3];
            #pragma unroll
            for (int ct = 0; ct < 6; ++ct) {
                bf16x8 b0 = *(const bf16x8*)&WL[(size_t)ct * 512 + lane * 8];
                bf16x8 b1 = *(const bf16x8*)&WL[(size_t)(6 + ct) * 512 + lane * 8];
                #pragma unroll
                for (int rt = 0; rt < 3; ++rt) {
                    acc[rt][ct] = __builtin_amdgcn_mfma_f32_16x16x32_bf16(aC[rt][0], b0, acc[rt][ct], 0, 0, 0);
                    acc[rt][ct] = __builtin_amdgcn_mfma_f32_16x16x32_bf16(aC[rt][1], b1, acc[rt][ct], 0, 0, 0);
                }
            }
        }

        // 4. barrier once per 2-tap superstep (drains staging for next one)
        if (idx & 1) __syncthreads();

        #pragma unroll
        for (int rt = 0; rt < 3; ++rt) { aC[rt][0] = aN[rt][0]; aC[rt][1] = aN[rt][1]; }
        sm_next = sm_next2;
        has_cur = has_next;
    }

    // ---- BN partial stats: lane -> wave shfl -> LDS cross-wave ----
    // sred = first 3 KB of Wlds (buf 0; last buf read was 26&3=2 -> safe)
    float s6[6], q6[6];
    #pragma unroll
    for (int ct = 0; ct < 6; ++ct) {
        float s = 0.f, q = 0.f;
        #pragma unroll
        for (int rt = 0; rt < 3; ++rt) {
            f32x4 a = acc[rt][ct];
            s += a[0] + a[1] + a[2] + a[3];
            q += a[0]*a[0] + a[1]*a[1] + a[2]*a[2] + a[3]*a[3];
        }
        s += __shfl_xor(s, 16); q += __shfl_xor(q, 16);
        s += __shfl_xor(s, 32); q += __shfl_xor(q, 32);
        s6[ct] = s; q6[ct] = q;
    }
    float* sred = (float*)Wlds;
    if (lane < 16) {
        #pragma unroll
        for (int ct = 0; ct < 6; ++ct) {
            sred[wid * 96 + ct * 16 + lane]       = s6[ct];
            sred[384 + wid * 96 + ct * 16 + lane] = q6[ct];
        }
    }
    __syncthreads();
    if (t < 96) {
        float s = sred[t] + sred[96 + t] + sred[192 + t] + sred[288 + t];
        pstats[(size_t)t * NBLK + blk] = s;
    } else if (t < 192) {
        int c = t - 96;
        float q = sred[384 + c] + sred[480 + c] + sred[576 + c] + sred[672 + c];
        pstats[(size_t)(96 + c) * NBLK + blk] = q;
    }

    // ---- store conv output ----
    #pragma unroll
    for (int rt = 0; rt < 3; ++rt) {
        #pragma unroll
        for (int ct = 0; ct < 6; ++ct) {
            #pragma unroll
            for (int j = 0; j < 4; ++j) {
                int row = rbase + rt * 16 + kgrp * 4 + j;
                if (row < N_VOX) {
                    if (STAGE_BF16)
                        stg[(size_t)row * OUTC + ct * 16 + row16] = f2bf(acc[rt][ct][j]);
                    else
                        outf[(size_t)row * OUTC + ct * 16 + row16] = acc[rt][ct][j];
                }
            }
        }
    }
}

__global__ void stats_reduce_kernel(const float* __restrict__ pstats,
                                    const float* __restrict__ gamma,
                                    const float* __restrict__ beta,
                                    float* __restrict__ scsh) {
    int c = blockIdx.x;               // 0..95
    int t = threadIdx.x;
    float s = 0.f, q = 0.f;
    for (int i = t; i < NBLK; i += 256) {
        s += pstats[(size_t)c * NBLK + i];
        q += pstats[(size_t)(96 + c) * NBLK + i];
    }
    #pragma unroll
    for (int d = 1; d < 64; d <<= 1) {
        s += __shfl_xor(s, d);
        q += __shfl_xor(q, d);
    }
    __shared__ float rs[4], rq[4];
    if ((t & 63) == 0) { rs[t >> 6] = s; rq[t >> 6] = q; }
    __syncthreads();
    if (t == 0) {
        s = rs[0] + rs[1] + rs[2] + rs[3];
        q = rq[0] + rq[1] + rq[2] + rq[3];
        float inv_n = 1.0f / (float)N_VOX;
        float mean = s * inv_n;
        float var  = q * inv_n - mean * mean;
        float sc   = gamma[c] * rsqrtf(var + EPSV);
        scsh[c]      = sc;
        scsh[96 + c] = beta[c] - mean * sc;
    }
}

__global__ void apply_bn_bf16_kernel(const unsigned short* __restrict__ stg,
                                     float* __restrict__ out,
                                     const float* __restrict__ scsh) {
    __shared__ float sc[OUTC], sh[OUTC];
    int t = threadIdx.x;
    if (t < OUTC) { sc[t] = scsh[t]; sh[t] = scsh[96 + t]; }
    __syncthreads();
    const int total8 = N_VOX * OUTC / 8;
    for (int i = blockIdx.x * blockDim.x + t; i < total8; i += gridDim.x * blockDim.x) {
        bf16x8 v = *(const bf16x8*)(stg + (size_t)i * 8);
        int c = (i % 12) * 8;
        float o[8];
        #pragma unroll
        for (int j = 0; j < 8; ++j) {
            union { unsigned u; float f; } w; w.u = (unsigned)(unsigned short)v[j] << 16;
            o[j] = fmaxf(fmaf(w.f, sc[c + j], sh[c + j]), 0.f);
        }
        float4* dst = (float4*)(out + (size_t)i * 8);
        dst[0] = make_float4(o[0], o[1], o[2], o[3]);
        dst[1] = make_float4(o[4], o[5], o[6], o[7]);
    }
}

__global__ void apply_bn_fp32_kernel(float* __restrict__ out,
                                     const float* __restrict__ scsh) {
    __shared__ float sc[OUTC], sh[OUTC];
    int t = threadIdx.x;
    if (t < OUTC) { sc[t] = scsh[t]; sh[t] = scsh[96 + t]; }
    __syncthreads();
    const int total4 = N_VOX * OUTC / 4;
    for (int i = blockIdx.x * blockDim.x + t; i < total4; i += gridDim.x * blockDim.x) {
        float4 v = ((float4*)out)[i];
        int c = (i * 4) % OUTC;
        v.x = fmaxf(fmaf(v.x, sc[c    ], sh[c    ]), 0.f);
        v.y = fmaxf(fmaf(v.y, sc[c + 1], sh[c + 1]), 0.f);
        v.z = fmaxf(fmaf(v.z, sc[c + 2], sh[c + 2]), 0.f);
        v.w = fmaxf(fmaf(v.w, sc[c + 3], sh[c + 3]), 0.f);
        ((float4*)out)[i] = v;
    }
}

extern "C" void kernel_launch(void* const* d_in, const int* in_sizes, int n_in,
                              void* d_out, int out_size, void* d_ws, size_t ws_size,
                              hipStream_t stream) {
    const float* feats   = (const float*)d_in[0];
    const float* Wc      = (const float*)d_in[1];
    const float* Woff    = (const float*)d_in[2];
    const float* gamma   = (const float*)d_in[3];
    const float* beta    = (const float*)d_in[4];
    const int*   in_idx  = (const int*)d_in[5];
    const int*   out_idx = (const int*)d_in[6];
    const int P = in_sizes[5] / NOFF;

    char* w = (char*)d_ws;
    int* srcmap = (int*)w;                   w += (size_t)NOFF * NPAD * 4;    // 20.82 MB
    unsigned short* Wb = (unsigned short*)w; w += (size_t)27 * 6144 * 2;      // 332 KB
    float* pstats = (float*)w;               w += (size_t)192 * NBLK * 4;     // 0.8 MB
    float* scsh = (float*)w;                 w += 256 * 4;
    unsigned short* featsb = (unsigned short*)w;
    w += (size_t)(N_VOX + 1) * INC * 2;                                        // 25.6 MB (+pad row)
    unsigned short* stg = (unsigned short*)w;
    size_t need_stg = (size_t)(w - (char*)d_ws) + (size_t)N_VOX * OUTC * 2;   // +38.4 MB
    bool use_stg = (ws_size >= need_stg);

    hipMemsetAsync(srcmap, 0xFF, (size_t)NOFF * NPAD * 4, stream);
    hipMemsetAsync(featsb + (size_t)N_VOX * INC, 0, INC * 2, stream);         // zero pad row

    const int FCVT_BLOCKS = (N_VOX * INC / 8 + 255) / 256;
    const int fill_blocks = (NOFF * P + 255) / 256;
    const int WPREP_BLOCKS = (27 * 2 * 6 * 64 + 255) / 256;
    prep_kernel<<<FCVT_BLOCKS + fill_blocks + WPREP_BLOCKS, 256, 0, stream>>>(
        feats, Wc, Woff, in_idx, out_idx, P, fill_blocks, featsb, Wb, srcmap);

    float* out = (float*)d_out;
    if (use_stg) {
        conv_mfma_kernel<1><<<NBLK, 256, 0, stream>>>(featsb, Wb, srcmap, out, stg, pstats);
        stats_reduce_kernel<<<96, 256, 0, stream>>>(pstats, gamma, beta, scsh);
        apply_bn_bf16_kernel<<<2048, 256, 0, stream>>>(stg, out, scsh);
    } else {
        conv_mfma_kernel<0><<<NBLK, 256, 0, stream>>>(featsb, Wb, srcmap, out, stg, pstats);
        stats_reduce_kernel<<<96, 256, 0, stream>>>(pstats, gamma, beta, scsh);
        apply_bn_fp32_kernel<<<2048, 256, 0, stream>>>(out, scsh);
    }
}